// Round 4
// baseline (117.947 us; speedup 1.0000x reference)
//
#include <hip/hip_runtime.h>
#include <hip/hip_bf16.h>

#define CIN 256
#define CRED 64
#define NB 4
#define NN 4096

typedef float v4f __attribute__((ext_vector_type(4)));
typedef short v8s __attribute__((ext_vector_type(8)));
typedef unsigned short u16;
typedef u16 u16x4 __attribute__((ext_vector_type(4)));
typedef u16 u16x8 __attribute__((ext_vector_type(8)));
typedef unsigned int u32;

#define LOG2E 1.4426950408889634f

__device__ __forceinline__ u16 f2bf(float f) {
    union { float f; u32 u; } v; v.f = f;
    u32 r = (v.u + 0x7FFFu + ((v.u >> 16) & 1u)) >> 16;  // RNE
    return (u16)r;
}
__device__ __forceinline__ float bf2f(u16 s) {
    union { u32 u; float f; } v; v.u = ((u32)s) << 16;
    return v.f;
}
// packed f32x2 -> bf16x2 (v_cvt_pk_bf16_f32 on gfx950), low half = a
__device__ __forceinline__ u32 pkbf(float a, float b) {
    float2 f; f.x = a; f.y = b;
    __hip_bfloat162 h = __float22bfloat162_rn(f);
    union { __hip_bfloat162 h; u32 u; } c; c.h = h;
    return c.u;
}
__device__ __forceinline__ v4f mfma16(v8s a, v8s b, v4f c) {
    return __builtin_amdgcn_mfma_f32_16x16x32_bf16(a, b, c, 0, 0, 0);
}
__device__ __forceinline__ float fexp2(float x) {
#if __has_builtin(__builtin_amdgcn_exp2f)
    return __builtin_amdgcn_exp2f(x);
#else
    return exp2f(x);
#endif
}

// ------------- kernel 0: QKV weights -> bf16 (Wp handled inline in k_proj) --
__global__ __launch_bounds__(256) void k_wconv(const float* __restrict__ Wq,
                                               const float* __restrict__ Wk,
                                               const float* __restrict__ Wv,
                                               u16* __restrict__ Wb) {
    int t = threadIdx.x;
    int idx = (blockIdx.x * 256 + t) * 4;
    int row = idx >> 8;
    int mat = row >> 6, r = row & 63, col = idx & 255;
    const float* src = (mat == 0) ? Wq : (mat == 1) ? Wk : Wv;
    float4 v = *(const float4*)&src[r * 256 + col];
    float s = (mat == 0) ? (0.125f * LOG2E) : 1.0f;
    u16x4 o;
    o[0] = f2bf(v.x * s); o[1] = f2bf(v.y * s);
    o[2] = f2bf(v.z * s); o[3] = f2bf(v.w * s);
    *(u16x4*)&Wb[idx] = o;
}

// ------------- kernel 1: QKV projection via MFMA, 32 tokens/block -----------
// x tile staged in LDS as [cb=c/8][n] 16-byte groups, +1-slot pad per cb row.
// Q,K: (b,n,r) bf16 (Q scaled 0.125*log2e). V: (b,r,n) with key-permuted n
// inside each 64-tile: pos(key) = (s>>1)*32 + quad*8 + (s&1)*4 + g where
// key = s*16 + quad*4 + g. This makes flash's in-register exp(S^T) values
// land exactly on the PV A-fragment k-order (no P LDS round-trip).
__global__ __launch_bounds__(256) void k_qkvm(const float* __restrict__ x,
                                              const u16* __restrict__ Wb,
                                              u16* __restrict__ Q, u16* __restrict__ K,
                                              u16* __restrict__ V) {
    __shared__ __align__(16) u16 Xl[1056 * 8];   // (32 cb * 33 slots) * 8 u16 = 16.9 KB
    int t = threadIdx.x;
    int wv = t >> 6, lane = t & 63, c15 = lane & 15, quad = lane >> 4;
    int n0g = blockIdx.x * 32;
    int b = n0g >> 12, nb = n0g & 4095;
    const float* xb = x + ((size_t)b << 20);

    // stage: thread owns channels cb*8..+7 x tokens n4..n4+3
    {
        int cb = t >> 3, n4 = (t & 7) * 4;
        const float* px = xb + (size_t)(cb * 8) * 4096 + nb + n4;
        float4 f[8];
#pragma unroll
        for (int j = 0; j < 8; ++j)
            f[j] = *(const float4*)&px[(size_t)j * 4096];
#pragma unroll
        for (int i = 0; i < 4; ++i) {
            union { u16x8 v; u32 w[4]; } pk;
            pk.w[0] = pkbf(((const float*)&f[0])[i], ((const float*)&f[1])[i]);
            pk.w[1] = pkbf(((const float*)&f[2])[i], ((const float*)&f[3])[i]);
            pk.w[2] = pkbf(((const float*)&f[4])[i], ((const float*)&f[5])[i]);
            pk.w[3] = pkbf(((const float*)&f[6])[i], ((const float*)&f[7])[i]);
            *(u16x8*)&Xl[(size_t)(cb * 33 + n4 + i) * 8] = pk.v;
        }
    }
    __syncthreads();

    // A-frags from LDS: token = nt*16+c15, channels kc*32+quad*8..+7
    v8s Af[2][8];
#pragma unroll
    for (int nt = 0; nt < 2; ++nt)
#pragma unroll
        for (int kc = 0; kc < 8; ++kc)
            Af[nt][kc] = *(const v8s*)&Xl[(size_t)((kc * 4 + quad) * 33 + nt * 16 + c15) * 8];

    // wave wv -> output r-tiles 3wv..3wv+2 (0-3 Q, 4-7 K, 8-11 V)
#pragma unroll
    for (int rti = 0; rti < 3; ++rti) {
        int rt = wv * 3 + rti;
        const u16* wrow = Wb + (size_t)(rt * 16 + c15) * 256 + quad * 8;
        v8s Bf[8];
#pragma unroll
        for (int kc = 0; kc < 8; ++kc) Bf[kc] = *(const v8s*)&wrow[kc * 32];
#pragma unroll
        for (int nt = 0; nt < 2; ++nt) {
            v4f acc = {0.f, 0.f, 0.f, 0.f};
#pragma unroll
            for (int kc = 0; kc < 8; ++kc)
                acc = mfma16(Af[nt][kc], Bf[kc], acc);
            // C layout: row(n_local) = quad*4+g, col(r_local) = c15
            if (rt < 8) {
                u16* base = (rt < 4) ? Q : K;
                u16* dst = base + ((size_t)b << 18)
                         + (size_t)(nb + nt * 16 + quad * 4) * 64
                         + (rt & 3) * 16 + c15;
#pragma unroll
                for (int g = 0; g < 4; ++g) dst[g * 64] = f2bf(acc[g]);
            } else {
                // V permuted: key s-tile hi2 = ((nb+nt*16)>>4)&3
                // pos = (hi2>>1)*32 + quad*8 + (hi2&1)*4 + g  (g contiguous)
                int hi2 = ((nb + nt * 16) >> 4) & 3;
                size_t base = ((size_t)b * 64 + (rt - 8) * 16 + c15) * 4096
                            + (size_t)((nb + nt * 16) & ~63)
                            + (hi2 >> 1) * 32 + (hi2 & 1) * 4 + quad * 8;
                union { u16x4 v; u32 w[2]; } pv;
                pv.w[0] = pkbf(acc[0], acc[1]);
                pv.w[1] = pkbf(acc[2], acc[3]);
                *(u16x4*)&V[base] = pv.v;
            }
        }
    }
}

// ------------- kernel 2: flash attention, q-split-2 x key-split-2 -----------
// K/V tiles in LDS as unpadded [64][64] u16 with XOR swizzle:
//   byte(row,col) = row*128 + ((col*2) ^ ((row&7)<<4))
// global_load_lds writes linearly; swizzle baked into per-lane GLOBAL source
// address (rule #21). Wave (qh,kh) computes 64 q-rows x its 32-key half:
// halves LDS reads vs q-split-4 (each K/V tile element read 2x per block,
// not 4x). S^T = mfma(K, Q) keeps q lane-local; exp(S) values ARE the PV
// A-frag (V key-permutation). Row-sums on the matrix pipe via P x ones.
// Key-half partial O/L merged once at the end through LDS (reusing KV).
__global__ __launch_bounds__(256, 2) void k_flash(const u16* __restrict__ Q,
                                                  const u16* __restrict__ K,
                                                  const u16* __restrict__ V,
                                                  u16* __restrict__ OP,
                                                  float* __restrict__ Lb,
                                                  int sh) {
    __shared__ __align__(16) u16 KV[2][2][4096];   // [buf][K=0/V=1][64*64 swz]
    __shared__ __align__(16) v4f LshV[2][4][64];   // key-half L merge (8 KB)
    int t = threadIdx.x;
    int p = blockIdx.x & ((1u << sh) - 1);
    int tile = blockIdx.x >> sh;
    int b = tile >> 5;
    int n0 = (tile & 31) * 128;
    int wv = t >> 6;
    int lane = t & 63;
    int c15 = lane & 15;
    int quad = lane >> 4;
    int qh = wv >> 1, kh = wv & 1;
    int nw = n0 + qh * 64;
    const u16* Qb = Q + ((size_t)b << 18);
    const u16* Kb = K + ((size_t)b << 18);
    const u16* Vb = V + ((size_t)b << 18);

    v8s Qa[4][2];
#pragma unroll
    for (int rg = 0; rg < 4; ++rg)
#pragma unroll
        for (int c2 = 0; c2 < 2; ++c2)
            Qa[rg][c2] = *(const v8s*)&Qb[(size_t)(nw + rg * 16 + c15) * 64 + c2 * 32 + quad * 8];

    // all-ones bf16 B-fragment for row-sum MFMA
    union { u16x8 u; v8s s; } on;
#pragma unroll
    for (int j = 0; j < 8; ++j) on.u[j] = 0x3F80;

    v4f O[4][4];
    v4f Lacc[4];
#pragma unroll
    for (int rg = 0; rg < 4; ++rg) {
#pragma unroll
        for (int g = 0; g < 4; ++g) {
            Lacc[rg][g] = 0.f;
#pragma unroll
            for (int cg = 0; cg < 4; ++cg) O[rg][cg][g] = 0.f;
        }
    }

    int mlen = NN >> sh;
    int m0 = p * mlen;
    int iters = mlen >> 6;

    // --- DMA staging lane constants (all 4 waves co-stage full tiles) ---
    int lrow = lane >> 3;                       // 0..7
    int cs16 = (((lane & 7) ^ lrow) << 3);      // source col offset in u16
    const u16* gK = Kb + ((size_t)(wv * 16 + lrow) << 6) + cs16;   // + row*64
    const u16* gV = Vb + ((size_t)(wv * 16 + lrow) << 12) + cs16;  // + row*4096

    auto stage = [&](int buf, int mt) {
#pragma unroll
        for (int i = 0; i < 2; ++i) {
            __builtin_amdgcn_global_load_lds(
                (const __attribute__((address_space(1))) void*)(gK + ((size_t)(mt + i * 8) << 6)),
                (__attribute__((address_space(3))) void*)&KV[buf][0][(wv * 2 + i) << 9],
                16, 0, 0);
            __builtin_amdgcn_global_load_lds(
                (const __attribute__((address_space(1))) void*)(gV + ((size_t)i << 15) + mt),
                (__attribute__((address_space(3))) void*)&KV[buf][1][(wv * 2 + i) << 9],
                16, 0, 0);
        }
    };

    // --- read-side swizzled address constants ---
    int swz = (c15 & 7) << 4;
    int colK0 = (quad << 4) ^ swz;              // red c2=0 (bytes)
    int colK1 = colK0 ^ 64;                     // red c2=1
    int colV  = ((kh << 6) | (quad << 4)) ^ swz;  // key-half kh pos block
    int rbaseK = kh * 4096 + (c15 << 7);        // key row = kh*32 + s'*16 + c15
    int rbaseV = c15 << 7;                      // d row = cg*16 + c15

    stage(0, m0);
    __syncthreads();    // compiler drains vmcnt(0) before s_barrier

    for (int it = 0; it < iters; ++it) {
        int cur = it & 1;
        if (it + 1 < iters) stage(cur ^ 1, m0 + (it + 1) * 64);
        const char* KB = (const char*)&KV[cur][0][0];
        const char* VB = (const char*)&KV[cur][1][0];

        // S^T[key][q]: A = K-frag (rows = keys kh*32 + s'*16 + ..), B = Q-frag.
        // lane holds q = rg*16 + c15 (col), key16 = quad*4 + g (row).
        v4f S[4][2];
#pragma unroll
        for (int rg = 0; rg < 4; ++rg)
#pragma unroll
            for (int s = 0; s < 2; ++s)
#pragma unroll
                for (int g = 0; g < 4; ++g) S[rg][s][g] = 0.f;

        __builtin_amdgcn_s_setprio(1);
#pragma unroll
        for (int s = 0; s < 2; ++s) {
            v8s kb0 = *(const v8s*)(KB + rbaseK + s * 2048 + colK0);
            v8s kb1 = *(const v8s*)(KB + rbaseK + s * 2048 + colK1);
#pragma unroll
            for (int rg = 0; rg < 4; ++rg) {
                S[rg][s] = mfma16(kb0, Qa[rg][0], S[rg][s]);
                S[rg][s] = mfma16(kb1, Qa[rg][1], S[rg][s]);
            }
        }
        __builtin_amdgcn_s_setprio(0);

        // fixed-max softmax, fully in-register: Pa[rg] element j = s'*4+g
        // = exp2(S[rg][s'][g])  (matches V key-permutation within kh half)
        v8s Pa[4];
#pragma unroll
        for (int rg = 0; rg < 4; ++rg) {
            union { v8s s; u32 w[4]; } pk;
            pk.w[0] = pkbf(fexp2(S[rg][0][0]), fexp2(S[rg][0][1]));
            pk.w[1] = pkbf(fexp2(S[rg][0][2]), fexp2(S[rg][0][3]));
            pk.w[2] = pkbf(fexp2(S[rg][1][0]), fexp2(S[rg][1][1]));
            pk.w[3] = pkbf(fexp2(S[rg][1][2]), fexp2(S[rg][1][3]));
            Pa[rg] = pk.s;
        }

        __builtin_amdgcn_s_setprio(1);
#pragma unroll
        for (int cg = 0; cg < 4; ++cg) {
            v8s vb = *(const v8s*)(VB + (cg << 11) + rbaseV + colV);
#pragma unroll
            for (int rg = 0; rg < 4; ++rg)
                O[rg][cg] = mfma16(Pa[rg], vb, O[rg][cg]);
        }
        // row-sum on the matrix pipe: L += P . ones (this key-half)
#pragma unroll
        for (int rg = 0; rg < 4; ++rg)
            Lacc[rg] = mfma16(Pa[rg], on.s, Lacc[rg]);
        __builtin_amdgcn_s_setprio(0);
        __syncthreads();   // all waves done reading cur; DMA to nxt drained
    }

    // ---- merge key-half partials (kh=1 -> kh=0) through LDS ----
    float* Osh = (float*)&KV[0][0][0];          // 32 KB: 2 qh x 16 frags x 64 lanes x v4f
    if (kh) {
#pragma unroll
        for (int rg = 0; rg < 4; ++rg)
#pragma unroll
            for (int cg = 0; cg < 4; ++cg)
                *(v4f*)&Osh[(((qh * 16 + rg * 4 + cg) << 6) + lane) * 4] = O[rg][cg];
#pragma unroll
        for (int rg = 0; rg < 4; ++rg)
            LshV[qh][rg][lane] = Lacc[rg];
    }
    __syncthreads();
    if (!kh) {
#pragma unroll
        for (int rg = 0; rg < 4; ++rg) {
#pragma unroll
            for (int cg = 0; cg < 4; ++cg) {
                v4f o2 = *(const v4f*)&Osh[(((qh * 16 + rg * 4 + cg) << 6) + lane) * 4];
#pragma unroll
                for (int g = 0; g < 4; ++g) O[rg][cg][g] += o2[g];
            }
            v4f l2 = LshV[qh][rg][lane];
#pragma unroll
            for (int g = 0; g < 4; ++g) Lacc[rg][g] += l2[g];
        }

        u16* OPp = OP + (size_t)p * (NB * NN * 64) + (size_t)b * NN * 64;
#pragma unroll
        for (int rg = 0; rg < 4; ++rg)
#pragma unroll
            for (int cg = 0; cg < 4; ++cg)
#pragma unroll
                for (int g = 0; g < 4; ++g) {
                    int n = nw + rg * 16 + quad * 4 + g;
                    OPp[(size_t)n * 64 + cg * 16 + c15] = f2bf(O[rg][cg][g]);
                }
        // Lacc columns identical (B = ones): every lane holds its rows' sums
        if (c15 == 0) {
            float* Lp = Lb + (size_t)p * (NB * NN) + (size_t)b * NN;
#pragma unroll
            for (int rg = 0; rg < 4; ++rg)
#pragma unroll
                for (int g = 0; g < 4; ++g) {
                    int n = nw + rg * 16 + quad * 4 + g;
                    Lp[n] = Lacc[rg][g];
                }
        }
    }
}

// ------------- kernel 3: merge splits + Wp MFMA projection + residual -------
#define OMP 72
template <int NSP>
__global__ __launch_bounds__(256) void k_proj(const u16* __restrict__ OP,
                                              const float* __restrict__ Lb,
                                              const float* __restrict__ Wp,
                                              const float* __restrict__ x,
                                              float* __restrict__ out) {
    __shared__ __align__(16) u16 Om[32 * OMP];    // merged normalized O: [n][r]
    int t = threadIdx.x;
    int b = blockIdx.x >> 7;
    int n0 = (blockIdx.x & 127) * 32;

    {
        int n_l = t >> 3, r0 = (t & 7) * 8;
        size_t nidx = (size_t)b * NN + n0 + n_l;
        float o[8] = {0.f, 0.f, 0.f, 0.f, 0.f, 0.f, 0.f, 0.f};
        float l = 0.f;
#pragma unroll
        for (int p = 0; p < NSP; ++p) {
            u16x8 u = *(const u16x8*)&OP[((size_t)p * (NB * NN) + nidx) * 64 + r0];
#pragma unroll
            for (int j = 0; j < 8; ++j) o[j] += bf2f(u[j]);
            l += Lb[(size_t)p * (NB * NN) + nidx];
        }
        float inv = 1.0f / l;
        union { u16x8 v; u32 w[4]; } p2;
        p2.w[0] = pkbf(o[0] * inv, o[1] * inv);
        p2.w[1] = pkbf(o[2] * inv, o[3] * inv);
        p2.w[2] = pkbf(o[4] * inv, o[5] * inv);
        p2.w[3] = pkbf(o[6] * inv, o[7] * inv);
        *(u16x8*)&Om[n_l * OMP + r0] = p2.v;
    }
    __syncthreads();

    int lane = t & 63, wvv = t >> 6, c15 = lane & 15, quad = lane >> 4;
    v8s Bf[2][2];
#pragma unroll
    for (int nt = 0; nt < 2; ++nt) {
        Bf[nt][0] = *(const v8s*)&Om[(nt * 16 + c15) * OMP + quad * 8];
        Bf[nt][1] = *(const v8s*)&Om[(nt * 16 + c15) * OMP + 32 + quad * 8];
    }
#pragma unroll
    for (int ct0 = 0; ct0 < 4; ++ct0) {
        int ct = wvv * 4 + ct0;
        const float* wrow = Wp + (size_t)(ct * 16 + c15) * 64 + quad * 8;
        float4 wa = *(const float4*)&wrow[0];
        float4 wb = *(const float4*)&wrow[4];
        float4 wc = *(const float4*)&wrow[32];
        float4 wd = *(const float4*)&wrow[36];
        union { v8s s; u32 w[4]; } A0, A1;
        A0.w[0] = pkbf(wa.x, wa.y); A0.w[1] = pkbf(wa.z, wa.w);
        A0.w[2] = pkbf(wb.x, wb.y); A0.w[3] = pkbf(wb.z, wb.w);
        A1.w[0] = pkbf(wc.x, wc.y); A1.w[1] = pkbf(wc.z, wc.w);
        A1.w[2] = pkbf(wd.x, wd.y); A1.w[3] = pkbf(wd.z, wd.w);
#pragma unroll
        for (int nt = 0; nt < 2; ++nt) {
            v4f acc = {0.f, 0.f, 0.f, 0.f};
            acc = mfma16(A0.s, Bf[nt][0], acc);
            acc = mfma16(A1.s, Bf[nt][1], acc);
            size_t base = ((size_t)(b * 256 + ct * 16 + quad * 4)) * 4096 + n0 + nt * 16 + c15;
#pragma unroll
            for (int g = 0; g < 4; ++g)
                out[base + (size_t)g * 4096] = acc[g] + x[base + (size_t)g * 4096];
        }
    }
}

extern "C" void kernel_launch(void* const* d_in, const int* in_sizes, int n_in,
                              void* d_out, int out_size, void* d_ws, size_t ws_size,
                              hipStream_t stream) {
    const float* x  = (const float*)d_in[0];
    const float* Wq = (const float*)d_in[1];
    const float* Wk = (const float*)d_in[2];
    const float* Wv = (const float*)d_in[3];
    const float* Wp = (const float*)d_in[4];
    float* out = (float*)d_out;
    char* ws = (char*)d_ws;

    const int nsp = 4;          // 4 KV-splits
    const int sh = 2;

    u16* Wb  = (u16*)(ws);                                   // 96 KB
    u16* Q   = (u16*)(ws + 262144);                          // 2 MB
    u16* K   = (u16*)(ws + 262144 + 2097152);                // 2 MB
    u16* V   = (u16*)(ws + 262144 + 2 * 2097152);            // 2 MB
    u16* OP  = (u16*)(ws + 262144 + 3 * 2097152);            // nsp*2 MB
    float* Lbuf = (float*)(ws + 262144 + (size_t)(3 + nsp) * 2097152);

    k_wconv<<<48, 256, 0, stream>>>(Wq, Wk, Wv, Wb);
    k_qkvm<<<512, 256, 0, stream>>>(x, Wb, Q, K, V);
    k_flash<<<NB * 32 * nsp, 256, 0, stream>>>(Q, K, V, OP, Lbuf, sh);
    k_proj<4><<<NB * 128, 256, 0, stream>>>(OP, Lbuf, Wp, x, out);
}

// Round 5
// 117.606 us; speedup vs baseline: 1.0029x; 1.0029x over previous
//
#include <hip/hip_runtime.h>
#include <hip/hip_bf16.h>

#define CIN 256
#define CRED 64
#define NB 4
#define NN 4096

typedef float v4f __attribute__((ext_vector_type(4)));
typedef short v8s __attribute__((ext_vector_type(8)));
typedef unsigned short u16;
typedef u16 u16x4 __attribute__((ext_vector_type(4)));
typedef u16 u16x8 __attribute__((ext_vector_type(8)));
typedef unsigned int u32;

#define LOG2E 1.4426950408889634f

__device__ __forceinline__ u16 f2bf(float f) {
    union { float f; u32 u; } v; v.f = f;
    u32 r = (v.u + 0x7FFFu + ((v.u >> 16) & 1u)) >> 16;  // RNE
    return (u16)r;
}
__device__ __forceinline__ float bf2f(u16 s) {
    union { u32 u; float f; } v; v.u = ((u32)s) << 16;
    return v.f;
}
// packed f32x2 -> bf16x2 (v_cvt_pk_bf16_f32 on gfx950), low half = a
__device__ __forceinline__ u32 pkbf(float a, float b) {
    float2 f; f.x = a; f.y = b;
    __hip_bfloat162 h = __float22bfloat162_rn(f);
    union { __hip_bfloat162 h; u32 u; } c; c.h = h;
    return c.u;
}
__device__ __forceinline__ v4f mfma16(v8s a, v8s b, v4f c) {
    return __builtin_amdgcn_mfma_f32_16x16x32_bf16(a, b, c, 0, 0, 0);
}
__device__ __forceinline__ float fexp2(float x) {
#if __has_builtin(__builtin_amdgcn_exp2f)
    return __builtin_amdgcn_exp2f(x);
#else
    return exp2f(x);
#endif
}

// ------------- kernel 0: QKV weights -> bf16 (Wp handled inline in k_proj) --
__global__ __launch_bounds__(256) void k_wconv(const float* __restrict__ Wq,
                                               const float* __restrict__ Wk,
                                               const float* __restrict__ Wv,
                                               u16* __restrict__ Wb) {
    int t = threadIdx.x;
    int idx = (blockIdx.x * 256 + t) * 4;
    int row = idx >> 8;
    int mat = row >> 6, r = row & 63, col = idx & 255;
    const float* src = (mat == 0) ? Wq : (mat == 1) ? Wk : Wv;
    float4 v = *(const float4*)&src[r * 256 + col];
    float s = (mat == 0) ? (0.125f * LOG2E) : 1.0f;
    u16x4 o;
    o[0] = f2bf(v.x * s); o[1] = f2bf(v.y * s);
    o[2] = f2bf(v.z * s); o[3] = f2bf(v.w * s);
    *(u16x4*)&Wb[idx] = o;
}

// ------------- kernel 1: QKV projection via MFMA, 32 tokens/block -----------
// x tile staged in LDS as [cb=c/8][n] 16-byte groups, +1-slot pad per cb row.
// Q,K: (b,n,r) bf16 (Q scaled 0.125*log2e). V: (b,r,n) with key-permuted n
// inside each 64-tile: pos(key) = (s>>1)*32 + quad*8 + (s&1)*4 + g where
// key = s*16 + quad*4 + g. This makes flash's in-register exp(S^T) values
// land exactly on the PV A-fragment k-order (no P LDS round-trip).
__global__ __launch_bounds__(256) void k_qkvm(const float* __restrict__ x,
                                              const u16* __restrict__ Wb,
                                              u16* __restrict__ Q, u16* __restrict__ K,
                                              u16* __restrict__ V) {
    __shared__ __align__(16) u16 Xl[1056 * 8];   // (32 cb * 33 slots) * 8 u16 = 16.9 KB
    int t = threadIdx.x;
    int wv = t >> 6, lane = t & 63, c15 = lane & 15, quad = lane >> 4;
    int n0g = blockIdx.x * 32;
    int b = n0g >> 12, nb = n0g & 4095;
    const float* xb = x + ((size_t)b << 20);

    // stage: thread owns channels cb*8..+7 x tokens n4..n4+3
    {
        int cb = t >> 3, n4 = (t & 7) * 4;
        const float* px = xb + (size_t)(cb * 8) * 4096 + nb + n4;
        float4 f[8];
#pragma unroll
        for (int j = 0; j < 8; ++j)
            f[j] = *(const float4*)&px[(size_t)j * 4096];
#pragma unroll
        for (int i = 0; i < 4; ++i) {
            union { u16x8 v; u32 w[4]; } pk;
            pk.w[0] = pkbf(((const float*)&f[0])[i], ((const float*)&f[1])[i]);
            pk.w[1] = pkbf(((const float*)&f[2])[i], ((const float*)&f[3])[i]);
            pk.w[2] = pkbf(((const float*)&f[4])[i], ((const float*)&f[5])[i]);
            pk.w[3] = pkbf(((const float*)&f[6])[i], ((const float*)&f[7])[i]);
            *(u16x8*)&Xl[(size_t)(cb * 33 + n4 + i) * 8] = pk.v;
        }
    }
    __syncthreads();

    // A-frags from LDS: token = nt*16+c15, channels kc*32+quad*8..+7
    v8s Af[2][8];
#pragma unroll
    for (int nt = 0; nt < 2; ++nt)
#pragma unroll
        for (int kc = 0; kc < 8; ++kc)
            Af[nt][kc] = *(const v8s*)&Xl[(size_t)((kc * 4 + quad) * 33 + nt * 16 + c15) * 8];

    // wave wv -> output r-tiles 3wv..3wv+2 (0-3 Q, 4-7 K, 8-11 V)
#pragma unroll
    for (int rti = 0; rti < 3; ++rti) {
        int rt = wv * 3 + rti;
        const u16* wrow = Wb + (size_t)(rt * 16 + c15) * 256 + quad * 8;
        v8s Bf[8];
#pragma unroll
        for (int kc = 0; kc < 8; ++kc) Bf[kc] = *(const v8s*)&wrow[kc * 32];
#pragma unroll
        for (int nt = 0; nt < 2; ++nt) {
            v4f acc = {0.f, 0.f, 0.f, 0.f};
#pragma unroll
            for (int kc = 0; kc < 8; ++kc)
                acc = mfma16(Af[nt][kc], Bf[kc], acc);
            // C layout: row(n_local) = quad*4+g, col(r_local) = c15
            if (rt < 8) {
                u16* base = (rt < 4) ? Q : K;
                u16* dst = base + ((size_t)b << 18)
                         + (size_t)(nb + nt * 16 + quad * 4) * 64
                         + (rt & 3) * 16 + c15;
#pragma unroll
                for (int g = 0; g < 4; ++g) dst[g * 64] = f2bf(acc[g]);
            } else {
                // V permuted: key s-tile hi2 = ((nb+nt*16)>>4)&3
                // pos = (hi2>>1)*32 + quad*8 + (hi2&1)*4 + g  (g contiguous)
                int hi2 = ((nb + nt * 16) >> 4) & 3;
                size_t base = ((size_t)b * 64 + (rt - 8) * 16 + c15) * 4096
                            + (size_t)((nb + nt * 16) & ~63)
                            + (hi2 >> 1) * 32 + (hi2 & 1) * 4 + quad * 8;
                union { u16x4 v; u32 w[2]; } pv;
                pv.w[0] = pkbf(acc[0], acc[1]);
                pv.w[1] = pkbf(acc[2], acc[3]);
                *(u16x4*)&V[base] = pv.v;
            }
        }
    }
}

// ------------- kernel 2: flash attention, q-split-2 x key-split-2 -----------
// Same partition as R4 (addressing validated) but register-lean inner loop:
// S lives only as 2 transient v4f per rg (fused MFMA->exp->pack), removing
// the 32-VGPR S[4][2] array that likely pushed R4 past the 256-VGPR cap.
__global__ __launch_bounds__(256, 2) void k_flash(const u16* __restrict__ Q,
                                                  const u16* __restrict__ K,
                                                  const u16* __restrict__ V,
                                                  u16* __restrict__ OP,
                                                  float* __restrict__ Lb,
                                                  int sh) {
    __shared__ __align__(16) u16 KV[2][2][4096];   // [buf][K=0/V=1][64*64 swz]
    __shared__ __align__(16) v4f LshV[2][4][64];   // key-half L merge (8 KB)
    int t = threadIdx.x;
    int p = blockIdx.x & ((1u << sh) - 1);
    int tile = blockIdx.x >> sh;
    int b = tile >> 5;
    int n0 = (tile & 31) * 128;
    int wv = t >> 6;
    int lane = t & 63;
    int c15 = lane & 15;
    int quad = lane >> 4;
    int qh = wv >> 1, kh = wv & 1;
    int nw = n0 + qh * 64;
    const u16* Qb = Q + ((size_t)b << 18);
    const u16* Kb = K + ((size_t)b << 18);
    const u16* Vb = V + ((size_t)b << 18);

    v8s Qa[4][2];
#pragma unroll
    for (int rg = 0; rg < 4; ++rg)
#pragma unroll
        for (int c2 = 0; c2 < 2; ++c2)
            Qa[rg][c2] = *(const v8s*)&Qb[(size_t)(nw + rg * 16 + c15) * 64 + c2 * 32 + quad * 8];

    // all-ones bf16 B-fragment for row-sum MFMA
    union { u16x8 u; v8s s; } on;
#pragma unroll
    for (int j = 0; j < 8; ++j) on.u[j] = 0x3F80;

    v4f O[4][4];
    v4f Lacc[4];
#pragma unroll
    for (int rg = 0; rg < 4; ++rg) {
#pragma unroll
        for (int g = 0; g < 4; ++g) {
            Lacc[rg][g] = 0.f;
#pragma unroll
            for (int cg = 0; cg < 4; ++cg) O[rg][cg][g] = 0.f;
        }
    }

    int mlen = NN >> sh;
    int m0 = p * mlen;
    int iters = mlen >> 6;

    // --- DMA staging lane constants (all 4 waves co-stage full tiles) ---
    int lrow = lane >> 3;                       // 0..7
    int cs16 = (((lane & 7) ^ lrow) << 3);      // source col offset in u16
    const u16* gK = Kb + ((size_t)(wv * 16 + lrow) << 6) + cs16;   // + row*64
    const u16* gV = Vb + ((size_t)(wv * 16 + lrow) << 12) + cs16;  // + row*4096

    auto stage = [&](int buf, int mt) {
#pragma unroll
        for (int i = 0; i < 2; ++i) {
            __builtin_amdgcn_global_load_lds(
                (const __attribute__((address_space(1))) void*)(gK + ((size_t)(mt + i * 8) << 6)),
                (__attribute__((address_space(3))) void*)&KV[buf][0][(wv * 2 + i) << 9],
                16, 0, 0);
            __builtin_amdgcn_global_load_lds(
                (const __attribute__((address_space(1))) void*)(gV + ((size_t)i << 15) + mt),
                (__attribute__((address_space(3))) void*)&KV[buf][1][(wv * 2 + i) << 9],
                16, 0, 0);
        }
    };

    // --- read-side swizzled address constants ---
    int swz = (c15 & 7) << 4;
    int colK0 = (quad << 4) ^ swz;              // red c2=0 (bytes)
    int colK1 = colK0 ^ 64;                     // red c2=1
    int colV  = ((kh << 6) | (quad << 4)) ^ swz;  // key-half kh pos block
    int rbaseK = kh * 4096 + (c15 << 7);        // key row = kh*32 + s'*16 + c15
    int rbaseV = c15 << 7;                      // d row = cg*16 + c15

    stage(0, m0);
    __syncthreads();    // compiler drains vmcnt(0) before s_barrier

    for (int it = 0; it < iters; ++it) {
        int cur = it & 1;
        if (it + 1 < iters) stage(cur ^ 1, m0 + (it + 1) * 64);
        const char* KB = (const char*)&KV[cur][0][0];
        const char* VB = (const char*)&KV[cur][1][0];

        // load this wave's 4 K-fragments (32 keys x 64 red)
        v8s kb[2][2];
#pragma unroll
        for (int s = 0; s < 2; ++s) {
            kb[s][0] = *(const v8s*)(KB + rbaseK + s * 2048 + colK0);
            kb[s][1] = *(const v8s*)(KB + rbaseK + s * 2048 + colK1);
        }

        // fused S^T -> exp -> Pa per rg: transient S = 2 v4f only.
        // lane holds q = rg*16 + c15 (col), key16 = quad*4 + g (row);
        // Pa element j = s'*4 + g = exp2(S[s'][g]) (matches V permutation).
        v8s Pa[4];
        __builtin_amdgcn_s_setprio(1);
#pragma unroll
        for (int rg = 0; rg < 4; ++rg) {
            v4f S0 = {0.f, 0.f, 0.f, 0.f};
            v4f S1 = {0.f, 0.f, 0.f, 0.f};
            S0 = mfma16(kb[0][0], Qa[rg][0], S0);
            S0 = mfma16(kb[0][1], Qa[rg][1], S0);
            S1 = mfma16(kb[1][0], Qa[rg][0], S1);
            S1 = mfma16(kb[1][1], Qa[rg][1], S1);
            union { v8s s; u32 w[4]; } pk;
            pk.w[0] = pkbf(fexp2(S0[0]), fexp2(S0[1]));
            pk.w[1] = pkbf(fexp2(S0[2]), fexp2(S0[3]));
            pk.w[2] = pkbf(fexp2(S1[0]), fexp2(S1[1]));
            pk.w[3] = pkbf(fexp2(S1[2]), fexp2(S1[3]));
            Pa[rg] = pk.s;
        }

#pragma unroll
        for (int cg = 0; cg < 4; ++cg) {
            v8s vb = *(const v8s*)(VB + (cg << 11) + rbaseV + colV);
#pragma unroll
            for (int rg = 0; rg < 4; ++rg)
                O[rg][cg] = mfma16(Pa[rg], vb, O[rg][cg]);
        }
        // row-sum on the matrix pipe: L += P . ones (this key-half)
#pragma unroll
        for (int rg = 0; rg < 4; ++rg)
            Lacc[rg] = mfma16(Pa[rg], on.s, Lacc[rg]);
        __builtin_amdgcn_s_setprio(0);
        __syncthreads();   // all waves done reading cur; DMA to nxt drained
    }

    // ---- merge key-half partials (kh=1 -> kh=0) through LDS ----
    float* Osh = (float*)&KV[0][0][0];          // 32 KB: 2 qh x 16 frags x 64 lanes x v4f
    if (kh) {
#pragma unroll
        for (int rg = 0; rg < 4; ++rg)
#pragma unroll
            for (int cg = 0; cg < 4; ++cg)
                *(v4f*)&Osh[(((qh * 16 + rg * 4 + cg) << 6) + lane) * 4] = O[rg][cg];
#pragma unroll
        for (int rg = 0; rg < 4; ++rg)
            LshV[qh][rg][lane] = Lacc[rg];
    }
    __syncthreads();
    if (!kh) {
#pragma unroll
        for (int rg = 0; rg < 4; ++rg) {
#pragma unroll
            for (int cg = 0; cg < 4; ++cg) {
                v4f o2 = *(const v4f*)&Osh[(((qh * 16 + rg * 4 + cg) << 6) + lane) * 4];
#pragma unroll
                for (int g = 0; g < 4; ++g) O[rg][cg][g] += o2[g];
            }
            v4f l2 = LshV[qh][rg][lane];
#pragma unroll
            for (int g = 0; g < 4; ++g) Lacc[rg][g] += l2[g];
        }

        u16* OPp = OP + (size_t)p * (NB * NN * 64) + (size_t)b * NN * 64;
#pragma unroll
        for (int rg = 0; rg < 4; ++rg)
#pragma unroll
            for (int cg = 0; cg < 4; ++cg)
#pragma unroll
                for (int g = 0; g < 4; ++g) {
                    int n = nw + rg * 16 + quad * 4 + g;
                    OPp[(size_t)n * 64 + cg * 16 + c15] = f2bf(O[rg][cg][g]);
                }
        // Lacc columns identical (B = ones): every lane holds its rows' sums
        if (c15 == 0) {
            float* Lp = Lb + (size_t)p * (NB * NN) + (size_t)b * NN;
#pragma unroll
            for (int rg = 0; rg < 4; ++rg)
#pragma unroll
                for (int g = 0; g < 4; ++g) {
                    int n = nw + rg * 16 + quad * 4 + g;
                    Lp[n] = Lacc[rg][g];
                }
        }
    }
}

// ------------- kernel 3: merge splits + Wp MFMA projection + residual -------
#define OMP 72
template <int NSP>
__global__ __launch_bounds__(256) void k_proj(const u16* __restrict__ OP,
                                              const float* __restrict__ Lb,
                                              const float* __restrict__ Wp,
                                              const float* __restrict__ x,
                                              float* __restrict__ out) {
    __shared__ __align__(16) u16 Om[32 * OMP];    // merged normalized O: [n][r]
    int t = threadIdx.x;
    int b = blockIdx.x >> 7;
    int n0 = (blockIdx.x & 127) * 32;

    {
        int n_l = t >> 3, r0 = (t & 7) * 8;
        size_t nidx = (size_t)b * NN + n0 + n_l;
        float o[8] = {0.f, 0.f, 0.f, 0.f, 0.f, 0.f, 0.f, 0.f};
        float l = 0.f;
#pragma unroll
        for (int p = 0; p < NSP; ++p) {
            u16x8 u = *(const u16x8*)&OP[((size_t)p * (NB * NN) + nidx) * 64 + r0];
#pragma unroll
            for (int j = 0; j < 8; ++j) o[j] += bf2f(u[j]);
            l += Lb[(size_t)p * (NB * NN) + nidx];
        }
        float inv = 1.0f / l;
        union { u16x8 v; u32 w[4]; } p2;
        p2.w[0] = pkbf(o[0] * inv, o[1] * inv);
        p2.w[1] = pkbf(o[2] * inv, o[3] * inv);
        p2.w[2] = pkbf(o[4] * inv, o[5] * inv);
        p2.w[3] = pkbf(o[6] * inv, o[7] * inv);
        *(u16x8*)&Om[n_l * OMP + r0] = p2.v;
    }
    __syncthreads();

    int lane = t & 63, wvv = t >> 6, c15 = lane & 15, quad = lane >> 4;
    v8s Bf[2][2];
#pragma unroll
    for (int nt = 0; nt < 2; ++nt) {
        Bf[nt][0] = *(const v8s*)&Om[(nt * 16 + c15) * OMP + quad * 8];
        Bf[nt][1] = *(const v8s*)&Om[(nt * 16 + c15) * OMP + 32 + quad * 8];
    }
#pragma unroll
    for (int ct0 = 0; ct0 < 4; ++ct0) {
        int ct = wvv * 4 + ct0;
        const float* wrow = Wp + (size_t)(ct * 16 + c15) * 64 + quad * 8;
        float4 wa = *(const float4*)&wrow[0];
        float4 wb = *(const float4*)&wrow[4];
        float4 wc = *(const float4*)&wrow[32];
        float4 wd = *(const float4*)&wrow[36];
        union { v8s s; u32 w[4]; } A0, A1;
        A0.w[0] = pkbf(wa.x, wa.y); A0.w[1] = pkbf(wa.z, wa.w);
        A0.w[2] = pkbf(wb.x, wb.y); A0.w[3] = pkbf(wb.z, wb.w);
        A1.w[0] = pkbf(wc.x, wc.y); A1.w[1] = pkbf(wc.z, wc.w);
        A1.w[2] = pkbf(wd.x, wd.y); A1.w[3] = pkbf(wd.z, wd.w);
#pragma unroll
        for (int nt = 0; nt < 2; ++nt) {
            v4f acc = {0.f, 0.f, 0.f, 0.f};
            acc = mfma16(A0.s, Bf[nt][0], acc);
            acc = mfma16(A1.s, Bf[nt][1], acc);
            size_t base = ((size_t)(b * 256 + ct * 16 + quad * 4)) * 4096 + n0 + nt * 16 + c15;
#pragma unroll
            for (int g = 0; g < 4; ++g)
                out[base + (size_t)g * 4096] = acc[g] + x[base + (size_t)g * 4096];
        }
    }
}

extern "C" void kernel_launch(void* const* d_in, const int* in_sizes, int n_in,
                              void* d_out, int out_size, void* d_ws, size_t ws_size,
                              hipStream_t stream) {
    const float* x  = (const float*)d_in[0];
    const float* Wq = (const float*)d_in[1];
    const float* Wk = (const float*)d_in[2];
    const float* Wv = (const float*)d_in[3];
    const float* Wp = (const float*)d_in[4];
    float* out = (float*)d_out;
    char* ws = (char*)d_ws;

    const int nsp = 4;          // 4 KV-splits
    const int sh = 2;

    u16* Wb  = (u16*)(ws);                                   // 96 KB
    u16* Q   = (u16*)(ws + 262144);                          // 2 MB
    u16* K   = (u16*)(ws + 262144 + 2097152);                // 2 MB
    u16* V   = (u16*)(ws + 262144 + 2 * 2097152);            // 2 MB
    u16* OP  = (u16*)(ws + 262144 + 3 * 2097152);            // nsp*2 MB
    float* Lbuf = (float*)(ws + 262144 + (size_t)(3 + nsp) * 2097152);

    k_wconv<<<48, 256, 0, stream>>>(Wq, Wk, Wv, Wb);
    k_qkvm<<<512, 256, 0, stream>>>(x, Wb, Q, K, V);
    k_flash<<<NB * 32 * nsp, 256, 0, stream>>>(Q, K, V, OP, Lbuf, sh);
    k_proj<4><<<NB * 128, 256, 0, stream>>>(OP, Lbuf, Wp, x, out);
}

// Round 6
// 113.608 us; speedup vs baseline: 1.0382x; 1.0352x over previous
//
#include <hip/hip_runtime.h>
#include <hip/hip_bf16.h>

#define CIN 256
#define CRED 64
#define NB 4
#define NN 4096

typedef float v4f __attribute__((ext_vector_type(4)));
typedef short v8s __attribute__((ext_vector_type(8)));
typedef unsigned short u16;
typedef u16 u16x4 __attribute__((ext_vector_type(4)));
typedef u16 u16x8 __attribute__((ext_vector_type(8)));
typedef unsigned int u32;

#define LOG2E 1.4426950408889634f

__device__ __forceinline__ u16 f2bf(float f) {
    union { float f; u32 u; } v; v.f = f;
    u32 r = (v.u + 0x7FFFu + ((v.u >> 16) & 1u)) >> 16;  // RNE
    return (u16)r;
}
__device__ __forceinline__ float bf2f(u16 s) {
    union { u32 u; float f; } v; v.u = ((u32)s) << 16;
    return v.f;
}
// packed f32x2 -> bf16x2 (v_cvt_pk_bf16_f32 on gfx950), low half = a
__device__ __forceinline__ u32 pkbf(float a, float b) {
    float2 f; f.x = a; f.y = b;
    __hip_bfloat162 h = __float22bfloat162_rn(f);
    union { __hip_bfloat162 h; u32 u; } c; c.h = h;
    return c.u;
}
__device__ __forceinline__ v4f mfma16(v8s a, v8s b, v4f c) {
    return __builtin_amdgcn_mfma_f32_16x16x32_bf16(a, b, c, 0, 0, 0);
}
__device__ __forceinline__ float fexp2(float x) {
#if __has_builtin(__builtin_amdgcn_exp2f)
    return __builtin_amdgcn_exp2f(x);
#else
    return exp2f(x);
#endif
}

// ------------- kernel 0: QKV weights -> bf16 (Wp handled inline in k_proj) --
__global__ __launch_bounds__(256) void k_wconv(const float* __restrict__ Wq,
                                               const float* __restrict__ Wk,
                                               const float* __restrict__ Wv,
                                               u16* __restrict__ Wb) {
    int t = threadIdx.x;
    int idx = (blockIdx.x * 256 + t) * 4;
    int row = idx >> 8;
    int mat = row >> 6, r = row & 63, col = idx & 255;
    const float* src = (mat == 0) ? Wq : (mat == 1) ? Wk : Wv;
    float4 v = *(const float4*)&src[r * 256 + col];
    float s = (mat == 0) ? (0.125f * LOG2E) : 1.0f;
    u16x4 o;
    o[0] = f2bf(v.x * s); o[1] = f2bf(v.y * s);
    o[2] = f2bf(v.z * s); o[3] = f2bf(v.w * s);
    *(u16x4*)&Wb[idx] = o;
}

// ------------- kernel 1: QKV projection via MFMA, 32 tokens/block -----------
// x tile staged in LDS as [cb=c/8][n] 16-byte groups, +1-slot pad per cb row.
// Q,K: (b,n,r) bf16 (Q scaled 0.125*log2e). V: (b,r,n) with key-permuted n
// inside each 64-tile: pos(key) = (s>>1)*32 + quad*8 + (s&1)*4 + g where
// key = s*16 + quad*4 + g. This makes flash's in-register exp(S^T) values
// land exactly on the PV A-fragment k-order (no P LDS round-trip).
__global__ __launch_bounds__(256) void k_qkvm(const float* __restrict__ x,
                                              const u16* __restrict__ Wb,
                                              u16* __restrict__ Q, u16* __restrict__ K,
                                              u16* __restrict__ V) {
    __shared__ __align__(16) u16 Xl[1056 * 8];   // (32 cb * 33 slots) * 8 u16 = 16.9 KB
    int t = threadIdx.x;
    int wv = t >> 6, lane = t & 63, c15 = lane & 15, quad = lane >> 4;
    int n0g = blockIdx.x * 32;
    int b = n0g >> 12, nb = n0g & 4095;
    const float* xb = x + ((size_t)b << 20);

    // stage: thread owns channels cb*8..+7 x tokens n4..n4+3
    {
        int cb = t >> 3, n4 = (t & 7) * 4;
        const float* px = xb + (size_t)(cb * 8) * 4096 + nb + n4;
        float4 f[8];
#pragma unroll
        for (int j = 0; j < 8; ++j)
            f[j] = *(const float4*)&px[(size_t)j * 4096];
#pragma unroll
        for (int i = 0; i < 4; ++i) {
            union { u16x8 v; u32 w[4]; } pk;
            pk.w[0] = pkbf(((const float*)&f[0])[i], ((const float*)&f[1])[i]);
            pk.w[1] = pkbf(((const float*)&f[2])[i], ((const float*)&f[3])[i]);
            pk.w[2] = pkbf(((const float*)&f[4])[i], ((const float*)&f[5])[i]);
            pk.w[3] = pkbf(((const float*)&f[6])[i], ((const float*)&f[7])[i]);
            *(u16x8*)&Xl[(size_t)(cb * 33 + n4 + i) * 8] = pk.v;
        }
    }
    __syncthreads();

    // A-frags from LDS: token = nt*16+c15, channels kc*32+quad*8..+7
    v8s Af[2][8];
#pragma unroll
    for (int nt = 0; nt < 2; ++nt)
#pragma unroll
        for (int kc = 0; kc < 8; ++kc)
            Af[nt][kc] = *(const v8s*)&Xl[(size_t)((kc * 4 + quad) * 33 + nt * 16 + c15) * 8];

    // wave wv -> output r-tiles 3wv..3wv+2 (0-3 Q, 4-7 K, 8-11 V)
#pragma unroll
    for (int rti = 0; rti < 3; ++rti) {
        int rt = wv * 3 + rti;
        const u16* wrow = Wb + (size_t)(rt * 16 + c15) * 256 + quad * 8;
        v8s Bf[8];
#pragma unroll
        for (int kc = 0; kc < 8; ++kc) Bf[kc] = *(const v8s*)&wrow[kc * 32];
#pragma unroll
        for (int nt = 0; nt < 2; ++nt) {
            v4f acc = {0.f, 0.f, 0.f, 0.f};
#pragma unroll
            for (int kc = 0; kc < 8; ++kc)
                acc = mfma16(Af[nt][kc], Bf[kc], acc);
            // C layout: row(n_local) = quad*4+g, col(r_local) = c15
            if (rt < 8) {
                u16* base = (rt < 4) ? Q : K;
                u16* dst = base + ((size_t)b << 18)
                         + (size_t)(nb + nt * 16 + quad * 4) * 64
                         + (rt & 3) * 16 + c15;
#pragma unroll
                for (int g = 0; g < 4; ++g) dst[g * 64] = f2bf(acc[g]);
            } else {
                // V permuted: key s-tile hi2 = ((nb+nt*16)>>4)&3
                // pos = (hi2>>1)*32 + quad*8 + (hi2&1)*4 + g  (g contiguous)
                int hi2 = ((nb + nt * 16) >> 4) & 3;
                size_t base = ((size_t)b * 64 + (rt - 8) * 16 + c15) * 4096
                            + (size_t)((nb + nt * 16) & ~63)
                            + (hi2 >> 1) * 32 + (hi2 & 1) * 4 + quad * 8;
                union { u16x4 v; u32 w[2]; } pv;
                pv.w[0] = pkbf(acc[0], acc[1]);
                pv.w[1] = pkbf(acc[2], acc[3]);
                *(u16x4*)&V[base] = pv.v;
            }
        }
    }
}

// ------------- kernel 2: flash attention, swapped-QK^T, in-register P -------
// R3 structure (validated best): q-split-4, each wave owns 32 q-rows and the
// full 64-key tile. K/V tiles in LDS as unpadded [64][64] u16 with XOR swz:
//   byte(row,col) = row*128 + ((col*2) ^ ((row&7)<<4))
// global_load_lds writes linearly; swizzle baked into per-lane GLOBAL source
// address (rule #21). S^T = mfma(K, Q) lands q lane-local (col=c15); with the
// V key-permutation, exp(S) values ARE the PV A-frag -> P never touches LDS.
// Row-sums accumulate on the matrix pipe via P x ones.
// __launch_bounds__(256,3): cap VGPR ~170 so 3 blocks/CU co-reside (the 3rd
// block hides the vmcnt-drain+barrier stall; reg arithmetic peaks ~150).
__global__ __launch_bounds__(256, 3) void k_flash(const u16* __restrict__ Q,
                                                  const u16* __restrict__ K,
                                                  const u16* __restrict__ V,
                                                  u16* __restrict__ OP,
                                                  float* __restrict__ Lb,
                                                  int sh) {
    __shared__ __align__(16) u16 KV[2][2][4096];   // [buf][K=0/V=1][64*64 swz]
    int t = threadIdx.x;
    int p = blockIdx.x & ((1u << sh) - 1);
    int tile = blockIdx.x >> sh;
    int b = tile >> 5;
    int n0 = (tile & 31) * 128;
    int wv = t >> 6;
    int lane = t & 63;
    int c15 = lane & 15;
    int quad = lane >> 4;
    int nw = n0 + wv * 32;
    const u16* Qb = Q + ((size_t)b << 18);
    const u16* Kb = K + ((size_t)b << 18);
    const u16* Vb = V + ((size_t)b << 18);

    v8s Qa[2][2];
#pragma unroll
    for (int rg = 0; rg < 2; ++rg)
#pragma unroll
        for (int c2 = 0; c2 < 2; ++c2)
            Qa[rg][c2] = *(const v8s*)&Qb[(size_t)(nw + rg * 16 + c15) * 64 + c2 * 32 + quad * 8];

    // all-ones bf16 B-fragment for row-sum MFMA
    union { u16x8 u; v8s s; } on;
#pragma unroll
    for (int j = 0; j < 8; ++j) on.u[j] = 0x3F80;

    v4f O[2][4];
    v4f Lacc[2];
#pragma unroll
    for (int rg = 0; rg < 2; ++rg) {
#pragma unroll
        for (int g = 0; g < 4; ++g) {
            Lacc[rg][g] = 0.f;
#pragma unroll
            for (int cg = 0; cg < 4; ++cg) O[rg][cg][g] = 0.f;
        }
    }

    int mlen = NN >> sh;
    int m0 = p * mlen;
    int iters = mlen >> 6;

    // --- DMA staging lane constants ---
    int lrow = lane >> 3;                       // 0..7
    int cs16 = (((lane & 7) ^ lrow) << 3);      // source col offset in u16
    const u16* gK = Kb + ((size_t)(wv * 16 + lrow) << 6) + cs16;   // + row*64
    const u16* gV = Vb + ((size_t)(wv * 16 + lrow) << 12) + cs16;  // + row*4096

    auto stage = [&](int buf, int mt) {
#pragma unroll
        for (int i = 0; i < 2; ++i) {
            __builtin_amdgcn_global_load_lds(
                (const __attribute__((address_space(1))) void*)(gK + ((size_t)(mt + i * 8) << 6)),
                (__attribute__((address_space(3))) void*)&KV[buf][0][(wv * 2 + i) << 9],
                16, 0, 0);
            __builtin_amdgcn_global_load_lds(
                (const __attribute__((address_space(1))) void*)(gV + ((size_t)i << 15) + mt),
                (__attribute__((address_space(3))) void*)&KV[buf][1][(wv * 2 + i) << 9],
                16, 0, 0);
        }
    };

    // --- read-side swizzled address constants ---
    int swz = (c15 & 7) << 4;
    int col0 = (quad << 4) ^ swz;       // c2=0 col bytes
    int col1 = col0 ^ 64;               // c2=1
    int rbase = c15 << 7;

    stage(0, m0);
    __syncthreads();    // compiler drains vmcnt(0) before s_barrier

    for (int it = 0; it < iters; ++it) {
        int cur = it & 1;
        if (it + 1 < iters) stage(cur ^ 1, m0 + (it + 1) * 64);
        const char* KB = (const char*)&KV[cur][0][0];
        const char* VB = (const char*)&KV[cur][1][0];

        // S^T[key][q]: A = K-frag (rows=key), B = Q-frag (cols=q).
        // lane holds q = rg*16 + c15, key = s*16 + quad*4 + g.
        v4f S[2][4];
#pragma unroll
        for (int rg = 0; rg < 2; ++rg)
#pragma unroll
            for (int s = 0; s < 4; ++s)
#pragma unroll
                for (int g = 0; g < 4; ++g) S[rg][s][g] = 0.f;

        __builtin_amdgcn_s_setprio(1);
#pragma unroll
        for (int s = 0; s < 4; ++s) {
            v8s kb0 = *(const v8s*)(KB + rbase + s * 2048 + col0);
            v8s kb1 = *(const v8s*)(KB + rbase + s * 2048 + col1);
            S[0][s] = mfma16(kb0, Qa[0][0], S[0][s]);
            S[1][s] = mfma16(kb0, Qa[1][0], S[1][s]);
            S[0][s] = mfma16(kb1, Qa[0][1], S[0][s]);
            S[1][s] = mfma16(kb1, Qa[1][1], S[1][s]);
        }
        __builtin_amdgcn_s_setprio(0);

        // fixed-max softmax, fully in-register: P A-frag element j of frag c2
        // = exp2(S[rg][s=c2*2+(j>>2)][g=j&3])  (matches V key-permutation)
        v8s Pa[2][2];
#pragma unroll
        for (int rg = 0; rg < 2; ++rg)
#pragma unroll
            for (int c2 = 0; c2 < 2; ++c2) {
                int s0 = c2 * 2, s1 = c2 * 2 + 1;
                union { v8s s; u32 w[4]; } pk;
                pk.w[0] = pkbf(fexp2(S[rg][s0][0]), fexp2(S[rg][s0][1]));
                pk.w[1] = pkbf(fexp2(S[rg][s0][2]), fexp2(S[rg][s0][3]));
                pk.w[2] = pkbf(fexp2(S[rg][s1][0]), fexp2(S[rg][s1][1]));
                pk.w[3] = pkbf(fexp2(S[rg][s1][2]), fexp2(S[rg][s1][3]));
                Pa[rg][c2] = pk.s;
            }

        __builtin_amdgcn_s_setprio(1);
#pragma unroll
        for (int cg = 0; cg < 4; ++cg) {
            v8s vb0 = *(const v8s*)(VB + (cg << 11) + rbase + col0);
            v8s vb1 = *(const v8s*)(VB + (cg << 11) + rbase + col1);
            O[0][cg] = mfma16(Pa[0][0], vb0, O[0][cg]);
            O[1][cg] = mfma16(Pa[1][0], vb0, O[1][cg]);
            O[0][cg] = mfma16(Pa[0][1], vb1, O[0][cg]);
            O[1][cg] = mfma16(Pa[1][1], vb1, O[1][cg]);
        }
        // row-sum on the matrix pipe: L += P . ones
        Lacc[0] = mfma16(Pa[0][0], on.s, Lacc[0]);
        Lacc[0] = mfma16(Pa[0][1], on.s, Lacc[0]);
        Lacc[1] = mfma16(Pa[1][0], on.s, Lacc[1]);
        Lacc[1] = mfma16(Pa[1][1], on.s, Lacc[1]);
        __builtin_amdgcn_s_setprio(0);
        __syncthreads();   // all waves done reading cur; DMA to nxt drained
    }

    u16* OPp = OP + (size_t)p * (NB * NN * 64) + (size_t)b * NN * 64;
#pragma unroll
    for (int rg = 0; rg < 2; ++rg)
#pragma unroll
        for (int cg = 0; cg < 4; ++cg)
#pragma unroll
            for (int g = 0; g < 4; ++g) {
                int n = nw + rg * 16 + quad * 4 + g;
                OPp[(size_t)n * 64 + cg * 16 + c15] = f2bf(O[rg][cg][g]);
            }
    // Lacc columns are identical (B = ones): every lane holds its rows' sums
    if (c15 == 0) {
        float* Lp = Lb + (size_t)p * (NB * NN) + (size_t)b * NN;
#pragma unroll
        for (int rg = 0; rg < 2; ++rg)
#pragma unroll
            for (int g = 0; g < 4; ++g) {
                int n = nw + rg * 16 + quad * 4 + g;
                Lp[n] = Lacc[rg][g];
            }
    }
}

// ------------- kernel 3: merge splits + Wp MFMA projection + residual -------
#define OMP 72
template <int NSP>
__global__ __launch_bounds__(256) void k_proj(const u16* __restrict__ OP,
                                              const float* __restrict__ Lb,
                                              const float* __restrict__ Wp,
                                              const float* __restrict__ x,
                                              float* __restrict__ out) {
    __shared__ __align__(16) u16 Om[32 * OMP];    // merged normalized O: [n][r]
    int t = threadIdx.x;
    int b = blockIdx.x >> 7;
    int n0 = (blockIdx.x & 127) * 32;

    {
        int n_l = t >> 3, r0 = (t & 7) * 8;
        size_t nidx = (size_t)b * NN + n0 + n_l;
        float o[8] = {0.f, 0.f, 0.f, 0.f, 0.f, 0.f, 0.f, 0.f};
        float l = 0.f;
#pragma unroll
        for (int p = 0; p < NSP; ++p) {
            u16x8 u = *(const u16x8*)&OP[((size_t)p * (NB * NN) + nidx) * 64 + r0];
#pragma unroll
            for (int j = 0; j < 8; ++j) o[j] += bf2f(u[j]);
            l += Lb[(size_t)p * (NB * NN) + nidx];
        }
        float inv = 1.0f / l;
        union { u16x8 v; u32 w[4]; } p2;
        p2.w[0] = pkbf(o[0] * inv, o[1] * inv);
        p2.w[1] = pkbf(o[2] * inv, o[3] * inv);
        p2.w[2] = pkbf(o[4] * inv, o[5] * inv);
        p2.w[3] = pkbf(o[6] * inv, o[7] * inv);
        *(u16x8*)&Om[n_l * OMP + r0] = p2.v;
    }
    __syncthreads();

    int lane = t & 63, wvv = t >> 6, c15 = lane & 15, quad = lane >> 4;
    v8s Bf[2][2];
#pragma unroll
    for (int nt = 0; nt < 2; ++nt) {
        Bf[nt][0] = *(const v8s*)&Om[(nt * 16 + c15) * OMP + quad * 8];
        Bf[nt][1] = *(const v8s*)&Om[(nt * 16 + c15) * OMP + 32 + quad * 8];
    }
#pragma unroll
    for (int ct0 = 0; ct0 < 4; ++ct0) {
        int ct = wvv * 4 + ct0;
        const float* wrow = Wp + (size_t)(ct * 16 + c15) * 64 + quad * 8;
        float4 wa = *(const float4*)&wrow[0];
        float4 wb = *(const float4*)&wrow[4];
        float4 wc = *(const float4*)&wrow[32];
        float4 wd = *(const float4*)&wrow[36];
        union { v8s s; u32 w[4]; } A0, A1;
        A0.w[0] = pkbf(wa.x, wa.y); A0.w[1] = pkbf(wa.z, wa.w);
        A0.w[2] = pkbf(wb.x, wb.y); A0.w[3] = pkbf(wb.z, wb.w);
        A1.w[0] = pkbf(wc.x, wc.y); A1.w[1] = pkbf(wc.z, wc.w);
        A1.w[2] = pkbf(wd.x, wd.y); A1.w[3] = pkbf(wd.z, wd.w);
#pragma unroll
        for (int nt = 0; nt < 2; ++nt) {
            v4f acc = {0.f, 0.f, 0.f, 0.f};
            acc = mfma16(A0.s, Bf[nt][0], acc);
            acc = mfma16(A1.s, Bf[nt][1], acc);
            size_t base = ((size_t)(b * 256 + ct * 16 + quad * 4)) * 4096 + n0 + nt * 16 + c15;
#pragma unroll
            for (int g = 0; g < 4; ++g)
                out[base + (size_t)g * 4096] = acc[g] + x[base + (size_t)g * 4096];
        }
    }
}

extern "C" void kernel_launch(void* const* d_in, const int* in_sizes, int n_in,
                              void* d_out, int out_size, void* d_ws, size_t ws_size,
                              hipStream_t stream) {
    const float* x  = (const float*)d_in[0];
    const float* Wq = (const float*)d_in[1];
    const float* Wk = (const float*)d_in[2];
    const float* Wv = (const float*)d_in[3];
    const float* Wp = (const float*)d_in[4];
    float* out = (float*)d_out;
    char* ws = (char*)d_ws;

    const int nsp = 4;          // 4 KV-splits
    const int sh = 2;

    u16* Wb  = (u16*)(ws);                                   // 96 KB
    u16* Q   = (u16*)(ws + 262144);                          // 2 MB
    u16* K   = (u16*)(ws + 262144 + 2097152);                // 2 MB
    u16* V   = (u16*)(ws + 262144 + 2 * 2097152);            // 2 MB
    u16* OP  = (u16*)(ws + 262144 + 3 * 2097152);            // nsp*2 MB
    float* Lbuf = (float*)(ws + 262144 + (size_t)(3 + nsp) * 2097152);

    k_wconv<<<48, 256, 0, stream>>>(Wq, Wk, Wv, Wb);
    k_qkvm<<<512, 256, 0, stream>>>(x, Wb, Q, K, V);
    k_flash<<<NB * 32 * nsp, 256, 0, stream>>>(Q, K, V, OP, Lbuf, sh);
    k_proj<4><<<NB * 128, 256, 0, stream>>>(OP, Lbuf, Wp, x, out);
}